// Round 5
// baseline (61.193 us; speedup 1.0000x reference)
//
#include <hip/hip_runtime.h>

// ClusteringLayer: q[n,k] = normalize_k( 1 / (1 + ||x_n - c_k||^2) )
// x: [65536,256] fp32, clusters: [256,256] fp32, out: [65536,256] fp32.
// R4: occupancy + store-path fix. 512-thr blocks (8 waves), wave owns 32
// cols (breg = 64 VGPR, truly resident), q transposed through swizzled
// LDS -> dwordx4 coalesced stores, grid 1024, 16 waves/CU.

typedef _Float16 f16x8 __attribute__((ext_vector_type(8)));
typedef _Float16 f16x4 __attribute__((ext_vector_type(4)));
typedef float    f32x4 __attribute__((ext_vector_type(4)));

#define DIM    256
#define NCLUST 256
#define BM     32      // rows per tile
#define NTILES 2       // tiles per block -> 64 rows/block

// ---------------------------------------------------------------------------
// Pre-kernel (unchanged): blocks 0..127 -> clusters fp32 -> f16 fragment order
//                         blocks 128..383 -> c2[j]
// Fragment f = s*16 + t; lane l holds
// B[col = t*16 + (l&15)][k = s*32 + (l>>4)*8 + v], v = 0..7.
// ---------------------------------------------------------------------------
__global__ __launch_bounds__(64) void pre_kernel(const float* __restrict__ clusters,
                                                 _Float16* __restrict__ bfrag,
                                                 float* __restrict__ c2) {
    int b = blockIdx.x;
    int l = threadIdx.x;
    if (b < 128) {
        int s   = b >> 4;
        int t   = b & 15;
        int col = t * 16 + (l & 15);
        int k0  = s * 32 + (l >> 4) * 8;
        const f32x4* p = reinterpret_cast<const f32x4*>(clusters + col * DIM + k0);
        f32x4 a = p[0];
        f32x4 c = p[1];
        f16x8 h;
        h[0] = (_Float16)a[0]; h[1] = (_Float16)a[1];
        h[2] = (_Float16)a[2]; h[3] = (_Float16)a[3];
        h[4] = (_Float16)c[0]; h[5] = (_Float16)c[1];
        h[6] = (_Float16)c[2]; h[7] = (_Float16)c[3];
        reinterpret_cast<f16x8*>(bfrag)[b * 64 + l] = h;
    } else {
        int j = b - 128;
        const f32x4* p = reinterpret_cast<const f32x4*>(clusters + j * DIM);
        f32x4 v = p[l];
        float s = v[0] * v[0] + v[1] * v[1] + v[2] * v[2] + v[3] * v[3];
#pragma unroll
        for (int m = 32; m >= 1; m >>= 1) s += __shfl_xor(s, m, 64);
        if (l == 0) c2[j] = s;
    }
}

// ---------------------------------------------------------------------------
// Main kernel: 1024 blocks x 512 threads (8 waves). Block owns 64 rows as
// 2 tiles of 32. Wave w owns cols [w*32, w*32+32) with B in registers.
// ---------------------------------------------------------------------------
__global__ __launch_bounds__(512, 4) void cluster_kernel(const float* __restrict__ x,
                                                         const f16x8* __restrict__ bfrag,
                                                         const float* __restrict__ c2,
                                                         float* __restrict__ out) {
    __shared__ _Float16 Xs[BM * DIM];       // 16 KB f16, XOR-swizzled rows
    __shared__ float    qlds[BM * NCLUST];  // 32 KB f32, col-XOR-swizzled
    __shared__ float    x2s[2][BM];
    __shared__ float    psum[8][BM];

    const int tid  = threadIdx.x;
    const int lane = tid & 63;
    const int wave = tid >> 6;
    const int cl   = lane & 15;
    const int g    = lane >> 4;
    const size_t rowbase = (size_t)blockIdx.x * (BM * NTILES);

    // ---- B fragments for this wave's 32 cols: 16 x 16B = 64 VGPRs ----
    f16x8 breg[16];
#pragma unroll
    for (int s = 0; s < 8; ++s)
#pragma unroll
        for (int t = 0; t < 2; ++t)
            breg[s * 2 + t] = bfrag[(s * 16 + wave * 2 + t) * 64 + lane];

    float c2v[2];
#pragma unroll
    for (int t = 0; t < 2; ++t) c2v[t] = c2[wave * 32 + t * 16 + cl];

    f32x4 ld[4];

    // ================= prologue: stage tile 0 =================
#pragma unroll
    for (int i = 0; i < 4; ++i) {
        int idx = i * 512 + tid;
        int r = idx >> 6, c4 = idx & 63;
        ld[i] = *reinterpret_cast<const f32x4*>(x + (rowbase + r) * DIM + c4 * 4);
    }
#pragma unroll
    for (int i = 0; i < 4; ++i) {
        int idx = i * 512 + tid;
        int r = idx >> 6, c4 = idx & 63;
        f32x4 a = ld[i];
        float s = a[0]*a[0] + a[1]*a[1] + a[2]*a[2] + a[3]*a[3];
        s += __shfl_xor(s, 1, 64);  s += __shfl_xor(s, 2, 64);
        s += __shfl_xor(s, 4, 64);  s += __shfl_xor(s, 8, 64);
        s += __shfl_xor(s, 16, 64); s += __shfl_xor(s, 32, 64);
        if (lane == 0) x2s[0][r] = s;
        f16x4 h;
        h[0] = (_Float16)a[0]; h[1] = (_Float16)a[1];
        h[2] = (_Float16)a[2]; h[3] = (_Float16)a[3];
        int g16 = c4 >> 1, sub = c4 & 1;
        int byte = r * 512 + ((g16 ^ (r & 7)) << 4) + sub * 8;
        *reinterpret_cast<f16x4*>(reinterpret_cast<char*>(Xs) + byte) = h;
    }
    __syncthreads();

    // ================= main loop over tiles =================
#pragma unroll 1
    for (int it = 0; it < NTILES; ++it) {
        const int buf = it & 1;

        // ---- T14: issue next tile's global loads now ----
        if (it + 1 < NTILES) {
#pragma unroll
            for (int i = 0; i < 4; ++i) {
                int idx = i * 512 + tid;
                int r = idx >> 6, c4 = idx & 63;
                ld[i] = *reinterpret_cast<const f32x4*>(
                    x + (rowbase + (it + 1) * BM + r) * DIM + c4 * 4);
            }
        }

        // ---- MFMA: 32 rows x 32 cols per wave ----
        f32x4 acc[2][2] = {};
        __builtin_amdgcn_s_setprio(1);
#pragma unroll
        for (int s = 0; s < 8; ++s) {
            f16x8 af[2];
#pragma unroll
            for (int rs = 0; rs < 2; ++rs) {
                int rr = rs * 16 + cl;
                af[rs] = *reinterpret_cast<const f16x8*>(
                    reinterpret_cast<const char*>(Xs)
                    + rr * 512 + (((s * 4 + g) ^ (rr & 7)) << 4));
            }
#pragma unroll
            for (int rs = 0; rs < 2; ++rs)
#pragma unroll
                for (int t = 0; t < 2; ++t)
                    acc[rs][t] = __builtin_amdgcn_mfma_f32_16x16x32_f16(
                        af[rs], breg[s * 2 + t], acc[rs][t], 0, 0, 0);
        }
        __builtin_amdgcn_s_setprio(0);

        // ---- epilogue A: q in regs, per-wave partial row sums ----
        // C/D layout: col = lane&15, row = (lane>>4)*4 + reg.
#pragma unroll
        for (int rs = 0; rs < 2; ++rs) {
            float rsum[4] = {0.f, 0.f, 0.f, 0.f};
#pragma unroll
            for (int j = 0; j < 4; ++j) {
                float x2j = x2s[buf][rs * 16 + g * 4 + j];
#pragma unroll
                for (int t = 0; t < 2; ++t) {
                    float d2 = 1.0f + x2j + c2v[t] - 2.0f * acc[rs][t][j];
                    float q  = __builtin_amdgcn_rcpf(d2);
                    acc[rs][t][j] = q;
                    rsum[j] += q;
                }
            }
#pragma unroll
            for (int j = 0; j < 4; ++j) {
                float v = rsum[j];
                v += __shfl_xor(v, 1, 64); v += __shfl_xor(v, 2, 64);
                v += __shfl_xor(v, 4, 64); v += __shfl_xor(v, 8, 64);
                if (cl == 0) psum[wave][rs * 16 + g * 4 + j] = v;
            }
        }
        __syncthreads();   // bar1: MFMA reads of Xs done; psum complete

        // ---- write phase: q -> qlds (swizzled), stage next tile -> Xs ----
#pragma unroll
        for (int rs = 0; rs < 2; ++rs)
#pragma unroll
            for (int j = 0; j < 4; ++j) {
                int rloc = rs * 16 + g * 4 + j;
                int swz  = ((rloc >> 2) & 3) << 4;
#pragma unroll
                for (int t = 0; t < 2; ++t) {
                    int col = wave * 32 + t * 16 + cl;
                    qlds[rloc * NCLUST + (col ^ swz)] = acc[rs][t][j];
                }
            }
        if (it + 1 < NTILES) {
#pragma unroll
            for (int i = 0; i < 4; ++i) {
                int idx = i * 512 + tid;
                int r = idx >> 6, c4 = idx & 63;
                f32x4 a = ld[i];
                float s = a[0]*a[0] + a[1]*a[1] + a[2]*a[2] + a[3]*a[3];
                s += __shfl_xor(s, 1, 64);  s += __shfl_xor(s, 2, 64);
                s += __shfl_xor(s, 4, 64);  s += __shfl_xor(s, 8, 64);
                s += __shfl_xor(s, 16, 64); s += __shfl_xor(s, 32, 64);
                if (lane == 0) x2s[buf ^ 1][r] = s;
                f16x4 h;
                h[0] = (_Float16)a[0]; h[1] = (_Float16)a[1];
                h[2] = (_Float16)a[2]; h[3] = (_Float16)a[3];
                int g16 = c4 >> 1, sub = c4 & 1;
                int byte = r * 512 + ((g16 ^ (r & 7)) << 4) + sub * 8;
                *reinterpret_cast<f16x4*>(reinterpret_cast<char*>(Xs) + byte) = h;
            }
        }
        __syncthreads();   // bar2: qlds + Xs(t+1) ready

        // ---- epilogue B: normalize + coalesced dwordx4 stores ----
#pragma unroll
        for (int i = 0; i < 4; ++i) {
            int row = i * 8 + wave;            // one full row per wave-inst
            float tot = psum[0][row] + psum[1][row] + psum[2][row] + psum[3][row]
                      + psum[4][row] + psum[5][row] + psum[6][row] + psum[7][row];
            float rn = __builtin_amdgcn_rcpf(tot);
            int swz  = ((row >> 2) & 3) << 4;
            int col0 = (lane * 4) ^ swz;
            f32x4 qv = *reinterpret_cast<const f32x4*>(&qlds[row * NCLUST + col0]);
            qv[0] *= rn; qv[1] *= rn; qv[2] *= rn; qv[3] *= rn;
            *reinterpret_cast<f32x4*>(
                out + (rowbase + it * BM + row) * NCLUST + lane * 4) = qv;
        }
        if (it + 1 < NTILES) __syncthreads();   // bar3: protect qlds/psum reuse
    }
}

extern "C" void kernel_launch(void* const* d_in, const int* in_sizes, int n_in,
                              void* d_out, int out_size, void* d_ws, size_t ws_size,
                              hipStream_t stream) {
    const float* x        = (const float*)d_in[0];
    const float* clusters = (const float*)d_in[1];
    float* out = (float*)d_out;

    _Float16* bfrag = (_Float16*)d_ws;                       // 128*64*16B = 128 KB
    float*    c2    = (float*)((char*)d_ws + 128 * 64 * 16); // 1 KB

    pre_kernel<<<384, 64, 0, stream>>>(clusters, bfrag, c2);

    int nrows = in_sizes[0] / DIM;              // 65536
    int grid  = nrows / (BM * NTILES);          // 1024
    cluster_kernel<<<grid, 512, 0, stream>>>(x, (const f16x8*)bfrag, c2, out);
}

// Round 6
// 52.959 us; speedup vs baseline: 1.1555x; 1.1555x over previous
//
#include <hip/hip_runtime.h>

// ClusteringLayer: q[n,k] = normalize_k( 1 / (1 + ||x_n - c_k||^2) )
// x: [65536,256] fp32, clusters: [256,256] fp32, out: [65536,256] fp32.
// R5: R4 with the VGPR cap fixed. launch_bounds(512,2) -> 128 VGPR cap,
// breg[16] (64 VGPR) truly resident, 16 waves/CU. Direct sector-efficient
// stores (no qlds), (r&15) swizzle, psum transposed, 2 barriers/tile.

typedef _Float16 f16x8 __attribute__((ext_vector_type(8)));
typedef _Float16 f16x4 __attribute__((ext_vector_type(4)));
typedef float    f32x4 __attribute__((ext_vector_type(4)));

#define DIM    256
#define NCLUST 256
#define BM     32      // rows per tile
#define NTILES 2       // tiles per block -> 64 rows/block

// ---------------------------------------------------------------------------
// Pre-kernel: blocks 0..127 -> clusters fp32 -> f16 fragment order
//             blocks 128..383 -> c2[j]
// Fragment f = s*16 + T; lane l holds
// B[col = T*16 + (l&15)][k = s*32 + (l>>4)*8 + v], v = 0..7.
// ---------------------------------------------------------------------------
__global__ __launch_bounds__(64) void pre_kernel(const float* __restrict__ clusters,
                                                 _Float16* __restrict__ bfrag,
                                                 float* __restrict__ c2) {
    int b = blockIdx.x;
    int l = threadIdx.x;
    if (b < 128) {
        int s   = b >> 4;
        int t   = b & 15;
        int col = t * 16 + (l & 15);
        int k0  = s * 32 + (l >> 4) * 8;
        const f32x4* p = reinterpret_cast<const f32x4*>(clusters + col * DIM + k0);
        f32x4 a = p[0];
        f32x4 c = p[1];
        f16x8 h;
        h[0] = (_Float16)a[0]; h[1] = (_Float16)a[1];
        h[2] = (_Float16)a[2]; h[3] = (_Float16)a[3];
        h[4] = (_Float16)c[0]; h[5] = (_Float16)c[1];
        h[6] = (_Float16)c[2]; h[7] = (_Float16)c[3];
        reinterpret_cast<f16x8*>(bfrag)[b * 64 + l] = h;
    } else {
        int j = b - 128;
        const f32x4* p = reinterpret_cast<const f32x4*>(clusters + j * DIM);
        f32x4 v = p[l];
        float s = v[0] * v[0] + v[1] * v[1] + v[2] * v[2] + v[3] * v[3];
#pragma unroll
        for (int m = 32; m >= 1; m >>= 1) s += __shfl_xor(s, m, 64);
        if (l == 0) c2[j] = s;
    }
}

// ---------------------------------------------------------------------------
// Main kernel: 1024 blocks x 512 threads (8 waves). Block owns 64 rows as
// 2 tiles of 32. Wave w owns cols [w*32, w*32+32), B resident in registers.
// ---------------------------------------------------------------------------
__global__ __launch_bounds__(512, 2) void cluster_kernel(const float* __restrict__ x,
                                                         const f16x8* __restrict__ bfrag,
                                                         const float* __restrict__ c2,
                                                         float* __restrict__ out) {
    __shared__ _Float16 Xs[BM * DIM];       // 16 KB, (r&15) XOR-swizzled
    __shared__ float    x2s[2][BM];
    __shared__ float    psum[BM][8];        // transposed: row-major 8 partials

    const int tid  = threadIdx.x;
    const int lane = tid & 63;
    const int wave = tid >> 6;
    const int cl   = lane & 15;
    const int g    = lane >> 4;
    const size_t rowbase = (size_t)blockIdx.x * (BM * NTILES);

    // ---- B fragments for this wave's 32 cols: 16 x 16B = 64 VGPRs ----
    f16x8 breg[16];
#pragma unroll
    for (int s = 0; s < 8; ++s)
#pragma unroll
        for (int t = 0; t < 2; ++t)
            breg[s * 2 + t] = bfrag[(s * 16 + wave * 2 + t) * 64 + lane];

    float c2v[2];
#pragma unroll
    for (int t = 0; t < 2; ++t) c2v[t] = c2[wave * 32 + t * 16 + cl];

    f32x4 ld[4];

    // ================= prologue: stage tile 0 =================
#pragma unroll
    for (int i = 0; i < 4; ++i) {
        int idx = i * 512 + tid;
        int r = idx >> 6, c4 = idx & 63;
        ld[i] = *reinterpret_cast<const f32x4*>(x + (rowbase + r) * DIM + c4 * 4);
    }
#pragma unroll
    for (int i = 0; i < 4; ++i) {
        int idx = i * 512 + tid;
        int r = idx >> 6, c4 = idx & 63;   // whole wave shares one row r
        f32x4 a = ld[i];
        float s = a[0]*a[0] + a[1]*a[1] + a[2]*a[2] + a[3]*a[3];
        s += __shfl_xor(s, 1, 64);  s += __shfl_xor(s, 2, 64);
        s += __shfl_xor(s, 4, 64);  s += __shfl_xor(s, 8, 64);
        s += __shfl_xor(s, 16, 64); s += __shfl_xor(s, 32, 64);
        if (lane == 0) x2s[0][r] = s;
        f16x4 h;
        h[0] = (_Float16)a[0]; h[1] = (_Float16)a[1];
        h[2] = (_Float16)a[2]; h[3] = (_Float16)a[3];
        int g16 = c4 >> 1, sub = c4 & 1;
        int byte = r * 512 + ((g16 ^ (r & 15)) << 4) + sub * 8;
        *reinterpret_cast<f16x4*>(reinterpret_cast<char*>(Xs) + byte) = h;
    }
    __syncthreads();

    // ================= main loop over tiles =================
#pragma unroll 1
    for (int it = 0; it < NTILES; ++it) {
        const int buf = it & 1;

        // ---- T14: issue next tile's global loads now (written after bar1) ----
        if (it + 1 < NTILES) {
#pragma unroll
            for (int i = 0; i < 4; ++i) {
                int idx = i * 512 + tid;
                int r = idx >> 6, c4 = idx & 63;
                ld[i] = *reinterpret_cast<const f32x4*>(
                    x + (rowbase + (it + 1) * BM + r) * DIM + c4 * 4);
            }
        }

        // ---- MFMA: 32 rows x 32 cols per wave ----
        f32x4 acc[2][2] = {};
        __builtin_amdgcn_s_setprio(1);
#pragma unroll
        for (int s = 0; s < 8; ++s) {
            f16x8 af[2];
#pragma unroll
            for (int rs = 0; rs < 2; ++rs) {
                int rr = rs * 16 + cl;
                af[rs] = *reinterpret_cast<const f16x8*>(
                    reinterpret_cast<const char*>(Xs)
                    + rr * 512 + (((s * 4 + g) ^ (rr & 15)) << 4));
            }
#pragma unroll
            for (int rs = 0; rs < 2; ++rs)
#pragma unroll
                for (int t = 0; t < 2; ++t)
                    acc[rs][t] = __builtin_amdgcn_mfma_f32_16x16x32_f16(
                        af[rs], breg[s * 2 + t], acc[rs][t], 0, 0, 0);
        }
        __builtin_amdgcn_s_setprio(0);

        // ---- epilogue A: q in regs, per-wave partial row sums -> psum ----
        // C/D layout: col = lane&15, row = (lane>>4)*4 + reg.
#pragma unroll
        for (int rs = 0; rs < 2; ++rs) {
#pragma unroll
            for (int j = 0; j < 4; ++j) {
                float x2j = x2s[buf][rs * 16 + g * 4 + j];
                float rsum = 0.0f;
#pragma unroll
                for (int t = 0; t < 2; ++t) {
                    float d2 = 1.0f + x2j + c2v[t] - 2.0f * acc[rs][t][j];
                    float q  = __builtin_amdgcn_rcpf(d2);
                    acc[rs][t][j] = q;
                    rsum += q;
                }
                rsum += __shfl_xor(rsum, 1, 64); rsum += __shfl_xor(rsum, 2, 64);
                rsum += __shfl_xor(rsum, 4, 64); rsum += __shfl_xor(rsum, 8, 64);
                if (cl == 0) psum[rs * 16 + g * 4 + j][wave] = rsum;
            }
        }
        __syncthreads();   // bar1: MFMA reads of Xs done; psum complete

        // ---- stores (normalize from psum) + stage next tile into Xs ----
#pragma unroll
        for (int rs = 0; rs < 2; ++rs) {
#pragma unroll
            for (int j = 0; j < 4; ++j) {
                int rloc = rs * 16 + g * 4 + j;
                const f32x4* pp = reinterpret_cast<const f32x4*>(&psum[rloc][0]);
                f32x4 p0 = pp[0], p1 = pp[1];
                float tot = (p0[0] + p0[1]) + (p0[2] + p0[3])
                          + (p1[0] + p1[1]) + (p1[2] + p1[3]);
                float rn = __builtin_amdgcn_rcpf(tot);
                float* op = out + (rowbase + it * BM + rloc) * NCLUST
                                + wave * 32 + cl;
                op[0]  = acc[rs][0][j] * rn;
                op[16] = acc[rs][1][j] * rn;
            }
        }
        if (it + 1 < NTILES) {
#pragma unroll
            for (int i = 0; i < 4; ++i) {
                int idx = i * 512 + tid;
                int r = idx >> 6, c4 = idx & 63;
                f32x4 a = ld[i];
                float s = a[0]*a[0] + a[1]*a[1] + a[2]*a[2] + a[3]*a[3];
                s += __shfl_xor(s, 1, 64);  s += __shfl_xor(s, 2, 64);
                s += __shfl_xor(s, 4, 64);  s += __shfl_xor(s, 8, 64);
                s += __shfl_xor(s, 16, 64); s += __shfl_xor(s, 32, 64);
                if (lane == 0) x2s[buf ^ 1][r] = s;
                f16x4 h;
                h[0] = (_Float16)a[0]; h[1] = (_Float16)a[1];
                h[2] = (_Float16)a[2]; h[3] = (_Float16)a[3];
                int g16 = c4 >> 1, sub = c4 & 1;
                int byte = r * 512 + ((g16 ^ (r & 15)) << 4) + sub * 8;
                *reinterpret_cast<f16x4*>(reinterpret_cast<char*>(Xs) + byte) = h;
            }
        }
        __syncthreads();   // bar2: Xs(t+1)/x2s ready; psum safe to reuse
    }
}

extern "C" void kernel_launch(void* const* d_in, const int* in_sizes, int n_in,
                              void* d_out, int out_size, void* d_ws, size_t ws_size,
                              hipStream_t stream) {
    const float* x        = (const float*)d_in[0];
    const float* clusters = (const float*)d_in[1];
    float* out = (float*)d_out;

    _Float16* bfrag = (_Float16*)d_ws;                       // 128*64*16B = 128 KB
    float*    c2    = (float*)((char*)d_ws + 128 * 64 * 16); // 1 KB

    pre_kernel<<<384, 64, 0, stream>>>(clusters, bfrag, c2);

    int nrows = in_sizes[0] / DIM;              // 65536
    int grid  = nrows / (BM * NTILES);          // 1024
    cluster_kernel<<<grid, 512, 0, stream>>>(x, (const f16x8*)bfrag, c2, out);
}

// Round 7
// 41.009 us; speedup vs baseline: 1.4922x; 1.2914x over previous
//
#include <hip/hip_runtime.h>

// ClusteringLayer: q[n,k] = normalize_k( 1 / (1 + ||x_n - c_k||^2) )
// x: [65536,256] fp32, clusters: [256,256] fp32, out: [65536,256] fp32.
// R6: block-level pipelining. NTILES=1, grid 2048: stage 32 rows, 1 bar,
// MFMA, psum bar, store, retire. ~4 staggered blocks/CU hide all latency.
// breg (64 VGPR) resident, (r&15) swizzle, transposed psum, direct stores.

typedef _Float16 f16x8 __attribute__((ext_vector_type(8)));
typedef _Float16 f16x4 __attribute__((ext_vector_type(4)));
typedef float    f32x4 __attribute__((ext_vector_type(4)));

#define DIM    256
#define NCLUST 256
#define BM     32      // rows per block

// ---------------------------------------------------------------------------
// Pre-kernel: blocks 0..127 -> clusters fp32 -> f16 fragment order
//             blocks 128..383 -> c2[j]
// Fragment f = s*16 + T; lane l holds
// B[col = T*16 + (l&15)][k = s*32 + (l>>4)*8 + v], v = 0..7.
// ---------------------------------------------------------------------------
__global__ __launch_bounds__(64) void pre_kernel(const float* __restrict__ clusters,
                                                 _Float16* __restrict__ bfrag,
                                                 float* __restrict__ c2) {
    int b = blockIdx.x;
    int l = threadIdx.x;
    if (b < 128) {
        int s   = b >> 4;
        int t   = b & 15;
        int col = t * 16 + (l & 15);
        int k0  = s * 32 + (l >> 4) * 8;
        const f32x4* p = reinterpret_cast<const f32x4*>(clusters + col * DIM + k0);
        f32x4 a = p[0];
        f32x4 c = p[1];
        f16x8 h;
        h[0] = (_Float16)a[0]; h[1] = (_Float16)a[1];
        h[2] = (_Float16)a[2]; h[3] = (_Float16)a[3];
        h[4] = (_Float16)c[0]; h[5] = (_Float16)c[1];
        h[6] = (_Float16)c[2]; h[7] = (_Float16)c[3];
        reinterpret_cast<f16x8*>(bfrag)[b * 64 + l] = h;
    } else {
        int j = b - 128;
        const f32x4* p = reinterpret_cast<const f32x4*>(clusters + j * DIM);
        f32x4 v = p[l];
        float s = v[0] * v[0] + v[1] * v[1] + v[2] * v[2] + v[3] * v[3];
#pragma unroll
        for (int m = 32; m >= 1; m >>= 1) s += __shfl_xor(s, m, 64);
        if (l == 0) c2[j] = s;
    }
}

// ---------------------------------------------------------------------------
// Main kernel: 2048 blocks x 512 threads (8 waves). Block owns 32 rows.
// Wave w owns cols [w*32, w*32+32), B resident in registers (16 frags).
// Linear life: load -> stage -> bar -> MFMA -> psum -> bar -> store -> end.
// ---------------------------------------------------------------------------
__global__ __launch_bounds__(512, 2) void cluster_kernel(const float* __restrict__ x,
                                                         const f16x8* __restrict__ bfrag,
                                                         const float* __restrict__ c2,
                                                         float* __restrict__ out) {
    __shared__ _Float16 Xs[BM * DIM];       // 16 KB, (r&15) XOR-swizzled
    __shared__ float    x2s[BM];
    __shared__ float    psum[BM][8];        // row-major 8 wave-partials

    const int tid  = threadIdx.x;
    const int lane = tid & 63;
    const int wave = tid >> 6;
    const int cl   = lane & 15;
    const int g    = lane >> 4;
    const size_t rowbase = (size_t)blockIdx.x * BM;

    // ---- issue X loads first (longest latency): 4x f32x4 per thread ----
    f32x4 ld[4];
#pragma unroll
    for (int i = 0; i < 4; ++i) {
        int idx = i * 512 + tid;
        int r = idx >> 6, c4 = idx & 63;
        ld[i] = *reinterpret_cast<const f32x4*>(x + (rowbase + r) * DIM + c4 * 4);
    }

    // ---- B fragments for this wave's 32 cols: 16 x 16B = 64 VGPRs (L2-hot) ----
    f16x8 breg[16];
#pragma unroll
    for (int s = 0; s < 8; ++s)
#pragma unroll
        for (int t = 0; t < 2; ++t)
            breg[s * 2 + t] = bfrag[(s * 16 + wave * 2 + t) * 64 + lane];

    float c2v[2];
#pragma unroll
    for (int t = 0; t < 2; ++t) c2v[t] = c2[wave * 32 + t * 16 + cl];

    // ---- stage: x2 reduce + fp32->f16 swizzled LDS write ----
#pragma unroll
    for (int i = 0; i < 4; ++i) {
        int idx = i * 512 + tid;
        int r = idx >> 6, c4 = idx & 63;   // whole wave shares one row r
        f32x4 a = ld[i];
        float s = a[0]*a[0] + a[1]*a[1] + a[2]*a[2] + a[3]*a[3];
        s += __shfl_xor(s, 1, 64);  s += __shfl_xor(s, 2, 64);
        s += __shfl_xor(s, 4, 64);  s += __shfl_xor(s, 8, 64);
        s += __shfl_xor(s, 16, 64); s += __shfl_xor(s, 32, 64);
        if (lane == 0) x2s[r] = s;
        f16x4 h;
        h[0] = (_Float16)a[0]; h[1] = (_Float16)a[1];
        h[2] = (_Float16)a[2]; h[3] = (_Float16)a[3];
        int g16 = c4 >> 1, sub = c4 & 1;
        int byte = r * 512 + ((g16 ^ (r & 15)) << 4) + sub * 8;
        *reinterpret_cast<f16x4*>(reinterpret_cast<char*>(Xs) + byte) = h;
    }
    __syncthreads();   // bar1: Xs + x2s ready

    // ---- MFMA: 32 rows x 32 cols per wave ----
    f32x4 acc[2][2] = {};
    __builtin_amdgcn_s_setprio(1);
#pragma unroll
    for (int s = 0; s < 8; ++s) {
        f16x8 af[2];
#pragma unroll
        for (int rs = 0; rs < 2; ++rs) {
            int rr = rs * 16 + cl;
            af[rs] = *reinterpret_cast<const f16x8*>(
                reinterpret_cast<const char*>(Xs)
                + rr * 512 + (((s * 4 + g) ^ (rr & 15)) << 4));
        }
#pragma unroll
        for (int rs = 0; rs < 2; ++rs)
#pragma unroll
            for (int t = 0; t < 2; ++t)
                acc[rs][t] = __builtin_amdgcn_mfma_f32_16x16x32_f16(
                    af[rs], breg[s * 2 + t], acc[rs][t], 0, 0, 0);
    }
    __builtin_amdgcn_s_setprio(0);

    // ---- epilogue A: q in regs, per-wave partial row sums -> psum ----
    // C/D layout: col = lane&15, row = (lane>>4)*4 + reg.
#pragma unroll
    for (int rs = 0; rs < 2; ++rs) {
#pragma unroll
        for (int j = 0; j < 4; ++j) {
            float x2j = x2s[rs * 16 + g * 4 + j];
            float rsum = 0.0f;
#pragma unroll
            for (int t = 0; t < 2; ++t) {
                float d2 = 1.0f + x2j + c2v[t] - 2.0f * acc[rs][t][j];
                float q  = __builtin_amdgcn_rcpf(d2);
                acc[rs][t][j] = q;
                rsum += q;
            }
            rsum += __shfl_xor(rsum, 1, 64); rsum += __shfl_xor(rsum, 2, 64);
            rsum += __shfl_xor(rsum, 4, 64); rsum += __shfl_xor(rsum, 8, 64);
            if (cl == 0) psum[rs * 16 + g * 4 + j][wave] = rsum;
        }
    }
    __syncthreads();   // bar2: psum complete

    // ---- normalize + store (sector-efficient: 16-lane 64B segments) ----
#pragma unroll
    for (int rs = 0; rs < 2; ++rs) {
#pragma unroll
        for (int j = 0; j < 4; ++j) {
            int rloc = rs * 16 + g * 4 + j;
            const f32x4* pp = reinterpret_cast<const f32x4*>(&psum[rloc][0]);
            f32x4 p0 = pp[0], p1 = pp[1];
            float tot = (p0[0] + p0[1]) + (p0[2] + p0[3])
                      + (p1[0] + p1[1]) + (p1[2] + p1[3]);
            float rn = __builtin_amdgcn_rcpf(tot);
            float* op = out + (rowbase + rloc) * NCLUST + wave * 32 + cl;
            op[0]  = acc[rs][0][j] * rn;
            op[16] = acc[rs][1][j] * rn;
        }
    }
}

extern "C" void kernel_launch(void* const* d_in, const int* in_sizes, int n_in,
                              void* d_out, int out_size, void* d_ws, size_t ws_size,
                              hipStream_t stream) {
    const float* x        = (const float*)d_in[0];
    const float* clusters = (const float*)d_in[1];
    float* out = (float*)d_out;

    _Float16* bfrag = (_Float16*)d_ws;                       // 128*64*16B = 128 KB
    float*    c2    = (float*)((char*)d_ws + 128 * 64 * 16); // 1 KB

    pre_kernel<<<384, 64, 0, stream>>>(clusters, bfrag, c2);

    int nrows = in_sizes[0] / DIM;      // 65536
    int grid  = nrows / BM;             // 2048
    cluster_kernel<<<grid, 512, 0, stream>>>(x, (const f16x8*)bfrag, c2, out);
}

// Round 8
// 35.926 us; speedup vs baseline: 1.7033x; 1.1415x over previous
//
#include <hip/hip_runtime.h>

// ClusteringLayer: q[n,k] = normalize_k( 1 / (1 + ||x_n - c_k||^2) )
// x: [65536,256] fp32, clusters: [256,256] fp32, out: [65536,256] fp32.
// R7: barrier-free waves. B' = -2*clusters as f16 fragments in 128 KB LDS
// (staged once/block); wave owns 16 rows x 256 cols -> row-sum wave-local;
// A built in registers from sector-efficient global loads; 1 barrier total.
// Grid 256 x 512 (1 block/CU), 2 tiles/wave, tile-1 prefetched.

typedef _Float16 f16x8 __attribute__((ext_vector_type(8)));
typedef float    f32x4 __attribute__((ext_vector_type(4)));

#define DIM    256
#define NCLUST 256

// ---------------------------------------------------------------------------
// Pre-kernel: blocks 0..127 -> B' = (-2*clusters) as f16 fragments in ws
//             blocks 128..383 -> c2p1[j] = 1 + sum_d clusters[j][d]^2
// Fragment f = s*16 + t; lane l holds
// B'[col = t*16 + (l&15)][k = s*32 + (l>>4)*8 + v], v = 0..7.
// A uses the same (group,v)->k map, so any HW k-permutation cancels.
// ---------------------------------------------------------------------------
__global__ __launch_bounds__(64) void pre_kernel(const float* __restrict__ clusters,
                                                 _Float16* __restrict__ bfrag,
                                                 float* __restrict__ c2p1) {
    int b = blockIdx.x;
    int l = threadIdx.x;
    if (b < 128) {
        int s   = b >> 4;
        int t   = b & 15;
        int col = t * 16 + (l & 15);
        int k0  = s * 32 + (l >> 4) * 8;
        const f32x4* p = reinterpret_cast<const f32x4*>(clusters + col * DIM + k0);
        f32x4 a = p[0];
        f32x4 c = p[1];
        f16x8 h;
        h[0] = (_Float16)(-2.0f * a[0]); h[1] = (_Float16)(-2.0f * a[1]);
        h[2] = (_Float16)(-2.0f * a[2]); h[3] = (_Float16)(-2.0f * a[3]);
        h[4] = (_Float16)(-2.0f * c[0]); h[5] = (_Float16)(-2.0f * c[1]);
        h[6] = (_Float16)(-2.0f * c[2]); h[7] = (_Float16)(-2.0f * c[3]);
        reinterpret_cast<f16x8*>(bfrag)[b * 64 + l] = h;
    } else {
        int j = b - 128;
        const f32x4* p = reinterpret_cast<const f32x4*>(clusters + j * DIM);
        f32x4 v = p[l];
        float s = v[0] * v[0] + v[1] * v[1] + v[2] * v[2] + v[3] * v[3];
#pragma unroll
        for (int m = 32; m >= 1; m >>= 1) s += __shfl_xor(s, m, 64);
        if (l == 0) c2p1[j] = 1.0f + s;
    }
}

// ---------------------------------------------------------------------------
// Main kernel: 256 blocks x 512 threads (8 waves, 1 block/CU).
// Wave w: tiles (blockIdx*16 + w*2 + {0,1}), each 16 rows x 256 cols.
// acc = -2*x.c ; d = x2 + (1+c2) + acc ; q = rcp(d); wave-local row-norm.
// ---------------------------------------------------------------------------
__global__ __launch_bounds__(512, 2) void cluster_kernel(const float* __restrict__ x,
                                                         const f32x4* __restrict__ bfrag,
                                                         const float* __restrict__ c2p1,
                                                         float* __restrict__ out) {
    __shared__ __align__(16) _Float16 Bs[65536];   // 128 KB: 128 frags x 1 KB

    const int tid  = threadIdx.x;
    const int lane = tid & 63;
    const int wave = tid >> 6;
    const int cl   = lane & 15;
    const int g    = lane >> 4;
    const int tile0 = blockIdx.x * 16 + wave * 2;

    // ---- issue tile-0 X loads first (HBM, longest latency) ----
    f32x4 ld[16];
    {
        const float* xr = x + (size_t)(tile0 * 16 + cl) * DIM + g * 8;
#pragma unroll
        for (int s = 0; s < 8; ++s) {
            ld[2 * s]     = *reinterpret_cast<const f32x4*>(xr + s * 32);
            ld[2 * s + 1] = *reinterpret_cast<const f32x4*>(xr + s * 32 + 4);
        }
    }

    // ---- c2p1 for this lane's columns (L2-hot) ----
    float c2v[16];
#pragma unroll
    for (int t = 0; t < 16; ++t) c2v[t] = c2p1[t * 16 + cl];

    // ---- stage B' fragments into LDS (L2-hot source, coalesced) ----
    {
        f32x4* dst = reinterpret_cast<f32x4*>(Bs);
#pragma unroll
        for (int i = 0; i < 16; ++i) {
            int idx = i * 512 + tid;
            dst[idx] = bfrag[idx];
        }
    }
    __syncthreads();   // the only barrier

#pragma unroll
    for (int it = 0; it < 2; ++it) {
        // ---- build A fragments + x2 from ld ----
        f16x8 af[8];
        float x2p = 0.0f;
#pragma unroll
        for (int s = 0; s < 8; ++s) {
            f32x4 a = ld[2 * s], b = ld[2 * s + 1];
            x2p += a[0]*a[0] + a[1]*a[1] + a[2]*a[2] + a[3]*a[3]
                 + b[0]*b[0] + b[1]*b[1] + b[2]*b[2] + b[3]*b[3];
            af[s][0] = (_Float16)a[0]; af[s][1] = (_Float16)a[1];
            af[s][2] = (_Float16)a[2]; af[s][3] = (_Float16)a[3];
            af[s][4] = (_Float16)b[0]; af[s][5] = (_Float16)b[1];
            af[s][6] = (_Float16)b[2]; af[s][7] = (_Float16)b[3];
        }
        float x2full = x2p + __shfl_xor(x2p, 16, 64);
        x2full += __shfl_xor(x2full, 32, 64);      // x2 of row (tile*16 + cl)

        // ---- prefetch tile-1 X loads under tile-0 compute ----
        if (it == 0) {
            const float* xr = x + (size_t)((tile0 + 1) * 16 + cl) * DIM + g * 8;
#pragma unroll
            for (int s = 0; s < 8; ++s) {
                ld[2 * s]     = *reinterpret_cast<const f32x4*>(xr + s * 32);
                ld[2 * s + 1] = *reinterpret_cast<const f32x4*>(xr + s * 32 + 4);
            }
        }

        // ---- MFMA: 16 rows x 256 cols, B from LDS ----
        f32x4 acc[16];
#pragma unroll
        for (int t = 0; t < 16; ++t) {
            acc[t][0] = 0.f; acc[t][1] = 0.f; acc[t][2] = 0.f; acc[t][3] = 0.f;
        }
        const char* bsb = reinterpret_cast<const char*>(Bs) + lane * 16;
#pragma unroll
        for (int s = 0; s < 8; ++s) {
#pragma unroll
            for (int t = 0; t < 16; ++t) {
                f16x8 bf = *reinterpret_cast<const f16x8*>(bsb + (s * 16 + t) * 1024);
                acc[t] = __builtin_amdgcn_mfma_f32_16x16x32_f16(af[s], bf, acc[t], 0, 0, 0);
            }
        }

        // ---- epilogue: d = x2 + (1+c2) + acc ; q = rcp(d); row-normalize ----
        // C/D layout: col = lane&15, row = (lane>>4)*4 + reg.
        float x2j[4];
#pragma unroll
        for (int j = 0; j < 4; ++j) x2j[j] = __shfl(x2full, g * 4 + j, 64);

        float rsum[4] = {0.f, 0.f, 0.f, 0.f};
#pragma unroll
        for (int t = 0; t < 16; ++t) {
#pragma unroll
            for (int j = 0; j < 4; ++j) {
                float d = x2j[j] + c2v[t] + acc[t][j];
                float q = __builtin_amdgcn_rcpf(d);
                acc[t][j] = q;
                rsum[j] += q;
            }
        }
#pragma unroll
        for (int j = 0; j < 4; ++j) {
            float v = rsum[j];
            v += __shfl_xor(v, 1, 64); v += __shfl_xor(v, 2, 64);
            v += __shfl_xor(v, 4, 64); v += __shfl_xor(v, 8, 64);
            rsum[j] = __builtin_amdgcn_rcpf(v);
        }
        float* ob = out + (size_t)((tile0 + it) * 16) * NCLUST;
#pragma unroll
        for (int t = 0; t < 16; ++t)
#pragma unroll
            for (int j = 0; j < 4; ++j)
                ob[(g * 4 + j) * NCLUST + t * 16 + cl] = acc[t][j] * rsum[j];
    }
}

extern "C" void kernel_launch(void* const* d_in, const int* in_sizes, int n_in,
                              void* d_out, int out_size, void* d_ws, size_t ws_size,
                              hipStream_t stream) {
    const float* x        = (const float*)d_in[0];
    const float* clusters = (const float*)d_in[1];
    float* out = (float*)d_out;

    _Float16* bfrag = (_Float16*)d_ws;                       // 128*64*16B = 128 KB
    float*    c2p1  = (float*)((char*)d_ws + 128 * 64 * 16); // 1 KB

    pre_kernel<<<384, 64, 0, stream>>>(clusters, bfrag, c2p1);

    cluster_kernel<<<256, 512, 0, stream>>>(x, (const f32x4*)bfrag, c2p1, out);
}